// Round 10
// baseline (38.799 us; speedup 1.0000x reference)
//
#include <hip/hip_runtime.h>
#include <hip/hip_fp16.h>
#include <math.h>

typedef __attribute__((ext_vector_type(8))) _Float16 f16x8;
typedef __attribute__((ext_vector_type(4))) float f32x4;
typedef __attribute__((ext_vector_type(2))) float f32x2;

// constexpr float -> fp16 bits (positive normals + zero only; exact for our values)
static constexpr unsigned short f2h(float f) {
    if (f == 0.0f) return 0;
    unsigned u = __builtin_bit_cast(unsigned, f);
    int e = (int)((u >> 23) & 0xff) - 127 + 15;
    unsigned m = (u >> 13) & 0x3ff;
    return (unsigned short)((e << 10) | m);
}

static constexpr float tri12(int k) {            // triangular kernel, ksize=12
    if (k < 0 || k >= 12) return 0.0f;
    float d = (float)k - 5.5f; if (d < 0) d = -d;
    return 6.0f - d;                              // unnormalized; scale cancels in l2norm
}

// GEMM2 B-table: WXT[n=oy][k=y] (16x32)
struct alignas(16) WxTbl { unsigned short v[16 * 32]; };
static constexpr WxTbl gen_wx() {
    WxTbl t{};
    for (int n = 0; n < 16; ++n)
        for (int k = 0; k < 32; ++k)
            t.v[n * 32 + k] = f2h((n < 4) ? tri12(k - 8 * n + 3) : 0.0f);
    return t;
}
__device__ const WxTbl WXT = gen_wx();

// GEMM1 B-table for bin-pair layout: WX2[n=(h*4+ox)][k=2x+h'] = (h==h') ? tri(x-8ox+3) : 0
struct alignas(16) Wx2Tbl { unsigned short v[16 * 64]; };
static constexpr Wx2Tbl gen_wx2() {
    Wx2Tbl t{};
    for (int n = 0; n < 16; ++n)
        for (int k = 0; k < 64; ++k) {
            float w = 0.0f;
            if (n < 8) {
                const int h = n >> 2, ox = n & 3;
                const int x = k >> 1, hp = k & 1;
                if (hp == h) w = tri12(x - 8 * ox + 3);
            }
            t.v[n * 64 + k] = f2h(w);
        }
    return t;
}
__device__ const Wx2Tbl WX2 = gen_wx2();

// separable gaussian table G[i] = exp(-(i-15.5)^2/1024), constexpr Taylor
struct alignas(16) GTbl { float v[32]; };
static constexpr GTbl gen_g() {
    GTbl t{};
    for (int i = 0; i < 32; ++i) {
        double x = -((i - 15.5) * (i - 15.5)) / 1024.0;
        double s = 1.0, term = 1.0;
        for (int k = 1; k < 16; ++k) { term *= x / k; s += term; }
        t.v[i] = (float)s;
    }
    return t;
}
__device__ const GTbl GT = gen_g();

__global__ __launch_bounds__(256, 8) void sift_desc_kernel(
        const float* __restrict__ in, float* __restrict__ out) {
    // ang: 4 bin-pair planes x 32 y x 32 x dwords (lo=bin 2d, hi=bin 2d+1), 16 KB.
    // x-dword swizzled: physical dword-in-row = x ^ ((y&7)<<2)  (byte ^= ((y&7)<<4))
    __shared__ __align__(16) unsigned int angd[4096];
    __shared__ __align__(16) unsigned short r2[1024];   // [bin*4+ox][y] fp16, 2 KB

    const int b = blockIdx.x, tid = threadIdx.x;
    constexpr float EPS = 1e-10f;

    // ---- phase 0: column mapping — lane owns 4 vertical pixels (yb..yb+3, x) ----
    const int xx = tid & 31;
    const int yb = (tid >> 5) * 4;
    const float* gp = in + (size_t)b * 1024;
    const int rm = (yb > 0) ? yb - 1 : 0;
    const int rp = (yb < 28) ? yb + 4 : 31;
    const int xm = (xx > 0) ? xx - 1 : 0;
    const int xp = (xx < 31) ? xx + 1 : 31;

    const float* colp = gp + xx;
    const float c0 = colp[rm * 32];
    const float c1 = colp[yb * 32];
    const float c2 = colp[yb * 32 + 32];
    const float c3 = colp[yb * 32 + 64];
    const float c4 = colp[yb * 32 + 96];
    const float c5 = colp[rp * 32];
    const float* lp = gp + yb * 32 + xm;
    const float l0 = lp[0], l1 = lp[32], l2 = lp[64], l3 = lp[96];
    const float* rr = gp + yb * 32 + xp;
    const float r0 = rr[0], r1 = rr[32], r2v = rr[64], r3 = rr[96];

    const float4 gyv = *reinterpret_cast<const float4*>(GT.v + yb);
    const float gxw = GT.v[xx];

    // u = 2*gx, v = 2*gy (0.5 folded into mag)
    const f32x2 uP[2] = {{r0 - l0, r1 - l1}, {r2v - l2, r3 - l3}};
    const f32x2 vP[2] = {{c2 - c0, c3 - c1}, {c4 - c2, c5 - c3}};
    const f32x2 gP[2] = {{gyv.x, gyv.y}, {gyv.z, gyv.w}};

    #pragma unroll
    for (int h = 0; h < 2; ++h) {
        const f32x2 u = uP[h], v = vP[h];
        const f32x2 gw = gP[h] * gxw;                       // gaussian sep.
        const f32x2 m2 = u * u + v * v;
        const f32x2 marg = m2 * 0.25f + EPS;
        const f32x2 sq = {__builtin_amdgcn_sqrtf(marg.x), __builtin_amdgcn_sqrtf(marg.y)};
        const f32x2 mag = sq * gw;

        const f32x2 gxe = u + 2e-10f;
        const f32x2 ax = __builtin_elementwise_abs(gxe);
        const f32x2 ay = __builtin_elementwise_abs(v);
        const f32x2 mx = __builtin_elementwise_max(
            __builtin_elementwise_max(ax, ay), (f32x2)1e-35f);
        const f32x2 mn = __builtin_elementwise_min(ax, ay);
        const f32x2 rc = {__builtin_amdgcn_rcpf(mx.x), __builtin_amdgcn_rcpf(mx.y)};
        const f32x2 t = mn * rc;
        const f32x2 s = t * t;
        f32x2 pl = s * (-0.1083947f) + 0.2293632f;          // pre-scaled by 4/pi
        pl = s * pl + (-0.4205503f);
        pl = s * pl + 1.2730689f;
        const f32x2 p  = t * pl;                            // in-octant fraction [0,1]
        const f32x2 pc = 1.0f - p;

        #pragma unroll
        for (int e = 0; e < 2; ++e) {
            const int ssw = (ay[e] > ax[e]);
            const int sx  = (gxe[e] < 0.0f);
            const int sy  = (v[e] < 0.0f);
            const int bit0 = ssw ^ sx;
            const int oct  = ((sx << 1) | bit0) ^ (sy ? 7 : 0);   // = bin0
            const float w1 = (bit0 ^ sy) ? pc[e] : p[e];
            const float m1 = w1 * mag[e];
            const float m0 = mag[e] - m1;

            const __half2 hh2 = __float22half2_rn(make_float2(m0, m1));
            unsigned pk; __builtin_memcpy(&pk, &hh2, 4);

            const int odd16 = (oct & 1) << 4;
            const unsigned v1 = pk << odd16;                       // even: (m0,m1); odd: (0,m0)
            const unsigned v2 = (pk >> 16) & (unsigned)(-(oct & 1)); // odd: (m1,0); even: 0

            const int y = yb + 2 * h + e;
            const int sw = y * 32 + (xx ^ ((y & 7) << 2));         // swizzled dword offset
            const int i1 = sw + ((oct & 6) << 9);                  // plane oct>>1
            const int i2 = sw + (((oct + 2) & 6) << 9);            // plane (oct>>1 + 1)&3
            angd[i1] = v1;
            angd[i2] = v2;
            angd[i1 ^ 2048] = 0u;                                  // plane+2: always-zero bins
            angd[i2 ^ 2048] = 0u;
        }
    }
    __syncthreads();   // barrier 1: all 4096 dwords written

    // ---- GEMM1 (MFMA fp16, K=64 in 2 steps): x-pooling on bin-pair layout ----
    // A rows = (pair*32 + y) [128 rows], k = 2x+h'; C col n = (h*4+ox) for n<8.
    const int l = tid & 63, w = tid >> 6, g = l >> 4, n = l & 15;
    const f16x8 b0 = *reinterpret_cast<const f16x8*>(WX2.v + n * 64 + g * 8);
    const f16x8 b1 = *reinterpret_cast<const f16x8*>(WX2.v + n * 64 + 32 + g * 8);
    const f32x4 zacc = {0.f, 0.f, 0.f, 0.f};
    const int swz = (n & 7) << 2;
    unsigned int* r2d = reinterpret_cast<unsigned int*>(r2);

    #pragma unroll
    for (int tt = 0; tt < 2; ++tt) {
        const int T = w * 2 + tt;                       // row-tile 0..7
        const int arow = T * 16 + n;
        const int dwb = (arow >> 5) * 1024 + (arow & 31) * 32;
        const f16x8 a0 = *reinterpret_cast<const f16x8*>(
            reinterpret_cast<const unsigned short*>(angd + dwb + ((g * 4) ^ swz)));
        const f16x8 a1 = *reinterpret_cast<const f16x8*>(
            reinterpret_cast<const unsigned short*>(angd + dwb + ((16 + g * 4) ^ swz)));
        f32x4 acc = __builtin_amdgcn_mfma_f32_16x16x32_f16(a0, b0, zacc, 0, 0, 0);
        acc = __builtin_amdgcn_mfma_f32_16x16x32_f16(a1, b1, acc, 0, 0, 0);
        if (n < 8) {
            // C row = T*16 + 4g + reg -> pair = T>>1, y = (T&1)*16 + 4g + reg; col -> (h,ox)
            const int hb = n >> 2, ox = n & 3;
            const int y0 = (T & 1) * 16 + 4 * g;
            const int row2 = ((T >> 1) * 2 + hb) * 4 + ox;      // bin*4 + ox
            const __half2 p01 = __float22half2_rn(make_float2(acc[0], acc[1]));
            const __half2 p23 = __float22half2_rn(make_float2(acc[2], acc[3]));
            unsigned lo, hi;
            __builtin_memcpy(&lo, &p01, 4);
            __builtin_memcpy(&hi, &p23, 4);
            *reinterpret_cast<uint2*>(r2d + row2 * 16 + (y0 >> 1)) = make_uint2(lo, hi);
        }
    }
    __syncthreads();   // barrier 2: r2 complete
    if (tid >= 64) return;

    // ---- GEMM2 (wave 0): y-pooling. A = r2 (32x32), B = WXT ----
    const f16x8 bf2 = *reinterpret_cast<const f16x8*>(WXT.v + n * 32 + g * 8);
    const f16x8 fa0 = *reinterpret_cast<const f16x8*>(r2 + n * 32 + g * 8);
    const f16x8 fa1 = *reinterpret_cast<const f16x8*>(r2 + (16 + n) * 32 + g * 8);
    const f32x4 d0 = __builtin_amdgcn_mfma_f32_16x16x32_f16(fa0, bf2, zacc, 0, 0, 0);
    const f32x4 d1 = __builtin_amdgcn_mfma_f32_16x16x32_f16(fa1, bf2, zacc, 0, 0, 0);

    const bool act = (n < 4);
    float q0 = act ? d0[0] : 0.f, q1 = act ? d0[1] : 0.f;
    float q2 = act ? d0[2] : 0.f, q3 = act ? d0[3] : 0.f;
    float q4 = act ? d1[0] : 0.f, q5 = act ? d1[1] : 0.f;
    float q6 = act ? d1[2] : 0.f, q7 = act ? d1[3] : 0.f;

    // ---- norm chain in-wave: l2 -> clip(0,0.2) -> l2 -> l1 -> sqrt(+eps) ----
    float ss = q0*q0 + q1*q1 + q2*q2 + q3*q3 + q4*q4 + q5*q5 + q6*q6 + q7*q7;
    #pragma unroll
    for (int off = 32; off; off >>= 1) ss += __shfl_xor(ss, off);
    const float inv = __builtin_amdgcn_rcpf(fmaxf(__builtin_amdgcn_sqrtf(ss), 1e-12f));
    q0 = fminf(q0 * inv, 0.2f); q1 = fminf(q1 * inv, 0.2f);
    q2 = fminf(q2 * inv, 0.2f); q3 = fminf(q3 * inv, 0.2f);
    q4 = fminf(q4 * inv, 0.2f); q5 = fminf(q5 * inv, 0.2f);
    q6 = fminf(q6 * inv, 0.2f); q7 = fminf(q7 * inv, 0.2f);

    float ss2 = q0*q0 + q1*q1 + q2*q2 + q3*q3 + q4*q4 + q5*q5 + q6*q6 + q7*q7;
    #pragma unroll
    for (int off = 32; off; off >>= 1) ss2 += __shfl_xor(ss2, off);
    const float inv2 = __builtin_amdgcn_rcpf(fmaxf(__builtin_amdgcn_sqrtf(ss2), 1e-12f));
    q0 *= inv2; q1 *= inv2; q2 *= inv2; q3 *= inv2;
    q4 *= inv2; q5 *= inv2; q6 *= inv2; q7 *= inv2;

    float s1 = q0 + q1 + q2 + q3 + q4 + q5 + q6 + q7;
    #pragma unroll
    for (int off = 32; off; off >>= 1) s1 += __shfl_xor(s1, off);
    const float inv1 = __builtin_amdgcn_rcpf(fmaxf(s1, 1e-12f));
    q0 = __builtin_amdgcn_sqrtf(fmaf(q0, inv1, EPS));
    q1 = __builtin_amdgcn_sqrtf(fmaf(q1, inv1, EPS));
    q2 = __builtin_amdgcn_sqrtf(fmaf(q2, inv1, EPS));
    q3 = __builtin_amdgcn_sqrtf(fmaf(q3, inv1, EPS));
    q4 = __builtin_amdgcn_sqrtf(fmaf(q4, inv1, EPS));
    q5 = __builtin_amdgcn_sqrtf(fmaf(q5, inv1, EPS));
    q6 = __builtin_amdgcn_sqrtf(fmaf(q6, inv1, EPS));
    q7 = __builtin_amdgcn_sqrtf(fmaf(q7, inv1, EPS));

    if (act) {
        float* op = out + (size_t)b * 128 + 16 * g + 4 * n;
        *reinterpret_cast<float4*>(op)      = make_float4(q0, q1, q2, q3);
        *reinterpret_cast<float4*>(op + 64) = make_float4(q4, q5, q6, q7);
    }
}

extern "C" void kernel_launch(void* const* d_in, const int* in_sizes, int n_in,
                              void* d_out, int out_size, void* d_ws, size_t ws_size,
                              hipStream_t stream) {
    const float* in = (const float*)d_in[0];
    float* out = (float*)d_out;
    const int batch = in_sizes[0] / 1024;   // 32*32 per patch
    sift_desc_kernel<<<batch, 256, 0, stream>>>(in, out);
}

// Round 11
// 33.458 us; speedup vs baseline: 1.1596x; 1.1596x over previous
//
#include <hip/hip_runtime.h>
#include <hip/hip_fp16.h>
#include <math.h>

typedef __attribute__((ext_vector_type(8))) _Float16 f16x8;
typedef __attribute__((ext_vector_type(4))) float f32x4;
typedef __attribute__((ext_vector_type(2))) float f32x2;

// constexpr float -> fp16 bits (positive normals + zero only; exact for our values)
static constexpr unsigned short f2h(float f) {
    if (f == 0.0f) return 0;
    unsigned u = __builtin_bit_cast(unsigned, f);
    int e = (int)((u >> 23) & 0xff) - 127 + 15;
    unsigned m = (u >> 13) & 0x3ff;
    return (unsigned short)((e << 10) | m);
}

// triangular pooling table WXT[n][k] (fp16 bits); conv ksize=12, stride=8, pad=3
struct alignas(16) WxTbl { unsigned short v[16 * 32]; };
static constexpr WxTbl gen_wx() {
    WxTbl t{};
    for (int n = 0; n < 16; ++n)
        for (int k = 0; k < 32; ++k) {
            float w = 0.0f;
            if (n < 4) {
                int kk = k - 8 * n + 3;
                if (kk >= 0 && kk < 12) {
                    float d = (float)kk - 5.5f; if (d < 0) d = -d;
                    w = 6.0f - d;               // unnormalized tri; scale cancels in l2norm
                }
            }
            t.v[n * 32 + k] = f2h(w);
        }
    return t;
}
__device__ const WxTbl WXT = gen_wx();

// separable gaussian table G[i] = exp(-(i-15.5)^2/1024), constexpr Taylor
struct alignas(16) GTbl { float v[32]; };
static constexpr GTbl gen_g() {
    GTbl t{};
    for (int i = 0; i < 32; ++i) {
        double x = -((i - 15.5) * (i - 15.5)) / 1024.0;
        double s = 1.0, term = 1.0;
        for (int k = 1; k < 16; ++k) { term *= x / k; s += term; }
        t.v[i] = (float)s;
    }
    return t;
}
__device__ const GTbl GT = gen_g();

__global__ __launch_bounds__(256, 8) void sift_desc_kernel(
        const float* __restrict__ in, float* __restrict__ out) {
    __shared__ __align__(16) unsigned short ang[8192];  // [bin*32+y][x] fp16, 16 KB
    __shared__ __align__(16) unsigned short r2b[1024];  // [bin*4+ox][y] fp16, 2 KB

    const int b = blockIdx.x, tid = threadIdx.x;
    constexpr float EPS = 1e-10f;

    // zero-fill ang
    {
        const float4 z = make_float4(0.f, 0.f, 0.f, 0.f);
        float4* az = reinterpret_cast<float4*>(ang);
        az[tid] = z; az[tid + 256] = z; az[tid + 512] = z; az[tid + 768] = z;
    }

    // ---- phase 0: row-segment gradients from global (L3-resident) ----
    const int r  = tid >> 3;          // row 0..31
    const int sg = tid & 7;           // segment 0..7
    const int x0 = sg * 4;
    const float* gp = in + (size_t)b * 1024;
    const float4 cur = *reinterpret_cast<const float4*>(gp + r * 32 + x0);
    const int rup = (r > 0) ? r - 1 : 0, rdn = (r < 31) ? r + 1 : 31;
    const float4 up = *reinterpret_cast<const float4*>(gp + rup * 32 + x0);
    const float4 dn = *reinterpret_cast<const float4*>(gp + rdn * 32 + x0);
    const float gyw = GT.v[r];
    const float4 gxw4 = *reinterpret_cast<const float4*>(GT.v + x0);

    const float lfs = __shfl_up(cur.w, 1);
    const float rts = __shfl_down(cur.x, 1);
    const float lf = (sg == 0) ? cur.x : lfs;   // replicate-pad at x=0
    const float rt = (sg == 7) ? cur.w : rts;   // replicate-pad at x=31

    // u = 2*gx, v = 2*gy (0.5 folded into mag), as pixel pairs for packed fp32
    const f32x2 uP[2] = {{cur.y - lf, cur.z - cur.x}, {cur.w - cur.y, rt - cur.z}};
    const f32x2 vP[2] = {{dn.x - up.x, dn.y - up.y}, {dn.z - up.z, dn.w - up.w}};
    const f32x2 gP[2] = {{gxw4.x, gxw4.y}, {gxw4.z, gxw4.w}};

    __syncthreads();   // barrier 1: zero-fill visible before scatter

    // ---- weighted magnitude + octant soft-bin scatter (packed math) ----
    {
        const int base2 = (r * 32 + x0) * 2;
        char* angb = reinterpret_cast<char*>(ang);
        #pragma unroll
        for (int h = 0; h < 2; ++h) {
            const f32x2 u = uP[h], v = vP[h];
            const f32x2 gw = gP[h] * gyw;
            const f32x2 m2 = u * u + v * v;
            const f32x2 marg = m2 * 0.25f + EPS;
            const f32x2 sq = {__builtin_amdgcn_sqrtf(marg.x),
                              __builtin_amdgcn_sqrtf(marg.y)};
            const f32x2 mag = sq * gw;

            const f32x2 gxe = u + 2e-10f;
            const f32x2 ax = __builtin_elementwise_abs(gxe);
            const f32x2 ay = __builtin_elementwise_abs(v);
            const f32x2 mx = __builtin_elementwise_max(
                __builtin_elementwise_max(ax, ay), (f32x2)1e-35f);
            const f32x2 mn = __builtin_elementwise_min(ax, ay);
            const f32x2 rc = {__builtin_amdgcn_rcpf(mx.x),
                              __builtin_amdgcn_rcpf(mx.y)};
            const f32x2 t = mn * rc;
            const f32x2 s = t * t;
            f32x2 pl = s * (-0.1083947f) + 0.2293632f;          // pre-scaled by 4/pi
            pl = s * pl + (-0.4205503f);
            pl = s * pl + 1.2730689f;
            const f32x2 p  = t * pl;                            // in-octant fraction
            const f32x2 pc = 1.0f - p;

            #pragma unroll
            for (int e = 0; e < 2; ++e) {
                const int ssw = (ay[e] > ax[e]);
                const int sx  = (gxe[e] < 0.0f);
                const int sy  = (v[e] < 0.0f);
                const int bit0 = ssw ^ sx;
                const int oct  = ((sx << 1) | bit0) ^ (sy ? 7 : 0);   // = bin0
                const float w1 = (bit0 ^ sy) ? pc[e] : p[e];
                const float m1 = w1 * mag[e];
                const float m0 = mag[e] - m1;

                const __half2 hh = __float22half2_rn(make_float2(m0, m1));
                unsigned int pk; __builtin_memcpy(&pk, &hh, 4);
                const int t0 = oct << 11;
                const int t1 = (t0 + 2048) & 0x3FFF;
                const int off = base2 + 2 * (2 * h + e);
                *reinterpret_cast<unsigned short*>(angb + t0 + off) = (unsigned short)pk;
                *reinterpret_cast<unsigned short*>(angb + t1 + off) = (unsigned short)(pk >> 16);
            }
        }
    }
    __syncthreads();   // barrier 2: scatter complete

    // ---- GEMM1 (MFMA fp16): x-pooling. A = ang (256x32), B^T = WXT (16x32) ----
    const int l = tid & 63, w = tid >> 6, g = l >> 4, n = l & 15;
    const f16x8 bfrag = *reinterpret_cast<const f16x8*>(WXT.v + n * 32 + g * 8);
    {
        const f32x4 zacc = {0.f, 0.f, 0.f, 0.f};
        #pragma unroll
        for (int tt = 0; tt < 4; ++tt) {
            const int T = w * 4 + tt;                       // row-tile 0..15
            const f16x8 afrag = *reinterpret_cast<const f16x8*>(
                ang + (T * 16 + n) * 32 + g * 8);
            const f32x4 acc = __builtin_amdgcn_mfma_f32_16x16x32_f16(afrag, bfrag, zacc, 0, 0, 0);
            if (n < 4) {
                // C layout: row = T*16 + 4g + reg (= a*32 + y), col = n (= ox)
                const int row = T * 16 + 4 * g;
                const int a = row >> 5, y0 = row & 31;
                const __half2 p01 = __float22half2_rn(make_float2(acc[0], acc[1]));
                const __half2 p23 = __float22half2_rn(make_float2(acc[2], acc[3]));
                unsigned int lo, hi;
                __builtin_memcpy(&lo, &p01, 4);
                __builtin_memcpy(&hi, &p23, 4);
                // r2b[row2 = a*4+ox][y], fp16, row stride 32
                *reinterpret_cast<uint2*>(r2b + (a * 4 + n) * 32 + y0) = make_uint2(lo, hi);
            }
        }
    }
    __syncthreads();   // barrier 3: r2b complete
    if (tid >= 64) return;   // waves 1-3 done

    // ---- GEMM2 (wave 0): y-pooling. A = r2b (32x32), B^T = WXT (wy == wx) ----
    const f32x4 zacc = {0.f, 0.f, 0.f, 0.f};
    const f16x8 fa0 = *reinterpret_cast<const f16x8*>(r2b + (n)      * 32 + g * 8);
    const f16x8 fa1 = *reinterpret_cast<const f16x8*>(r2b + (16 + n) * 32 + g * 8);
    const f32x4 d0 = __builtin_amdgcn_mfma_f32_16x16x32_f16(fa0, bfrag, zacc, 0, 0, 0);
    const f32x4 d1 = __builtin_amdgcn_mfma_f32_16x16x32_f16(fa1, bfrag, zacc, 0, 0, 0);

    // lane (g,n), reg rr: d0 -> desc[a=g][oy=n][ox=rr], d1 -> desc[a=4+g][oy=n][ox=rr]
    const bool act = (n < 4);
    float q0 = act ? d0[0] : 0.f, q1 = act ? d0[1] : 0.f;
    float q2 = act ? d0[2] : 0.f, q3 = act ? d0[3] : 0.f;
    float q4 = act ? d1[0] : 0.f, q5 = act ? d1[1] : 0.f;
    float q6 = act ? d1[2] : 0.f, q7 = act ? d1[3] : 0.f;

    // ---- norm chain in-wave. Active lanes = {g*16+n, n<4} = coset of span{1,2,16,32},
    //      so xor-offsets 4,8 are redundant (inactive lanes carry exact zeros).
    float ss = q0*q0 + q1*q1 + q2*q2 + q3*q3 + q4*q4 + q5*q5 + q6*q6 + q7*q7;
    ss += __shfl_xor(ss, 1); ss += __shfl_xor(ss, 2);
    ss += __shfl_xor(ss, 16); ss += __shfl_xor(ss, 32);
    const float inv = __builtin_amdgcn_rcpf(fmaxf(__builtin_amdgcn_sqrtf(ss), 1e-12f));
    q0 = fminf(q0 * inv, 0.2f); q1 = fminf(q1 * inv, 0.2f);
    q2 = fminf(q2 * inv, 0.2f); q3 = fminf(q3 * inv, 0.2f);
    q4 = fminf(q4 * inv, 0.2f); q5 = fminf(q5 * inv, 0.2f);
    q6 = fminf(q6 * inv, 0.2f); q7 = fminf(q7 * inv, 0.2f);

    float ss2 = q0*q0 + q1*q1 + q2*q2 + q3*q3 + q4*q4 + q5*q5 + q6*q6 + q7*q7;
    ss2 += __shfl_xor(ss2, 1); ss2 += __shfl_xor(ss2, 2);
    ss2 += __shfl_xor(ss2, 16); ss2 += __shfl_xor(ss2, 32);
    const float inv2 = __builtin_amdgcn_rcpf(fmaxf(__builtin_amdgcn_sqrtf(ss2), 1e-12f));
    q0 *= inv2; q1 *= inv2; q2 *= inv2; q3 *= inv2;
    q4 *= inv2; q5 *= inv2; q6 *= inv2; q7 *= inv2;

    float s1 = q0 + q1 + q2 + q3 + q4 + q5 + q6 + q7;
    s1 += __shfl_xor(s1, 1); s1 += __shfl_xor(s1, 2);
    s1 += __shfl_xor(s1, 16); s1 += __shfl_xor(s1, 32);
    const float inv1 = __builtin_amdgcn_rcpf(fmaxf(s1, 1e-12f));
    q0 = __builtin_amdgcn_sqrtf(fmaf(q0, inv1, EPS));
    q1 = __builtin_amdgcn_sqrtf(fmaf(q1, inv1, EPS));
    q2 = __builtin_amdgcn_sqrtf(fmaf(q2, inv1, EPS));
    q3 = __builtin_amdgcn_sqrtf(fmaf(q3, inv1, EPS));
    q4 = __builtin_amdgcn_sqrtf(fmaf(q4, inv1, EPS));
    q5 = __builtin_amdgcn_sqrtf(fmaf(q5, inv1, EPS));
    q6 = __builtin_amdgcn_sqrtf(fmaf(q6, inv1, EPS));
    q7 = __builtin_amdgcn_sqrtf(fmaf(q7, inv1, EPS));

    if (act) {
        // out idx = a*16 + oy*4 + ox: (d0) 16g + 4n + rr, (d1) 64 + 16g + 4n + rr
        float* op = out + (size_t)b * 128 + 16 * g + 4 * n;
        *reinterpret_cast<float4*>(op)      = make_float4(q0, q1, q2, q3);
        *reinterpret_cast<float4*>(op + 64) = make_float4(q4, q5, q6, q7);
    }
}

extern "C" void kernel_launch(void* const* d_in, const int* in_sizes, int n_in,
                              void* d_out, int out_size, void* d_ws, size_t ws_size,
                              hipStream_t stream) {
    const float* in = (const float*)d_in[0];
    float* out = (float*)d_out;
    const int batch = in_sizes[0] / 1024;   // 32*32 per patch
    sift_desc_kernel<<<batch, 256, 0, stream>>>(in, out);
}

// Round 12
// 32.844 us; speedup vs baseline: 1.1813x; 1.0187x over previous
//
#include <hip/hip_runtime.h>
#include <hip/hip_fp16.h>
#include <math.h>

typedef __attribute__((ext_vector_type(8))) _Float16 f16x8;
typedef __attribute__((ext_vector_type(4))) float f32x4;
typedef __attribute__((ext_vector_type(2))) float f32x2;

// constexpr exp via Taylor (|x| < 1)
static constexpr double cexp(double x) {
    double s = 1.0, t = 1.0;
    for (int k = 1; k < 24; ++k) { t *= x / k; s += t; }
    return s;
}

// double -> fp16 bits, round-to-nearest (positive normals + zero; our values only)
static constexpr unsigned short f2h_rn(double dv) {
    float f = (float)dv;
    if (f == 0.0f) return 0;
    unsigned u = __builtin_bit_cast(unsigned, f);
    u += 0x1000;                                   // RN at fp16 mantissa boundary
    int e = (int)((u >> 23) & 0xff) - 127 + 15;
    unsigned m = (u >> 13) & 0x3ff;
    return (unsigned short)((e << 10) | m);
}

// Pooling table with gaussian FOLDED IN: W[n][k] = tri12(k-8n+3) * G[k], fp16.
// Serves GEMM1 (k=x, folds G[x]) AND GEMM2 (k=y, folds G[y]) — same geometry.
// tri unnormalized, gaussian unnormalized: global scales cancel in l2norm.
struct alignas(16) WxTbl { unsigned short v[16 * 32]; };
static constexpr WxTbl gen_wx() {
    WxTbl t{};
    for (int n = 0; n < 16; ++n)
        for (int k = 0; k < 32; ++k) {
            double w = 0.0;
            if (n < 4) {
                int kk = k - 8 * n + 3;            // conv ksize=12, stride=8, pad=3
                if (kk >= 0 && kk < 12) {
                    double d = (double)kk - 5.5; if (d < 0) d = -d;
                    w = (6.0 - d) * cexp(-((k - 15.5) * (k - 15.5)) / 1024.0);
                }
            }
            t.v[n * 32 + k] = f2h_rn(w);
        }
    return t;
}
__device__ const WxTbl WXT = gen_wx();

__global__ __launch_bounds__(256, 8) void sift_desc_kernel(
        const float* __restrict__ in, float* __restrict__ out) {
    __shared__ __align__(16) unsigned short ang[8192];  // [bin*32+y][x] fp16, 16 KB
    __shared__ __align__(16) unsigned short r2b[1024];  // [bin*4+ox][y] fp16, 2 KB

    const int b = blockIdx.x, tid = threadIdx.x;
    constexpr float EPS = 1e-10f;

    // zero-fill ang
    {
        const float4 z = make_float4(0.f, 0.f, 0.f, 0.f);
        float4* az = reinterpret_cast<float4*>(ang);
        az[tid] = z; az[tid + 256] = z; az[tid + 512] = z; az[tid + 768] = z;
    }

    // ---- phase 0: row-segment gradients from global (L3-resident) ----
    const int r  = tid >> 3;          // row 0..31
    const int sg = tid & 7;           // segment 0..7
    const int x0 = sg * 4;
    const float* gp = in + (size_t)b * 1024;
    const float4 cur = *reinterpret_cast<const float4*>(gp + r * 32 + x0);
    const int rup = (r > 0) ? r - 1 : 0, rdn = (r < 31) ? r + 1 : 31;
    const float4 up = *reinterpret_cast<const float4*>(gp + rup * 32 + x0);
    const float4 dn = *reinterpret_cast<const float4*>(gp + rdn * 32 + x0);

    const float lfs = __shfl_up(cur.w, 1);
    const float rts = __shfl_down(cur.x, 1);
    const float lf = (sg == 0) ? cur.x : lfs;   // replicate-pad at x=0
    const float rt = (sg == 7) ? cur.w : rts;   // replicate-pad at x=31

    // u = 2*gx, v = 2*gy (0.5 folded into mag; global scale cancels in l2norm)
    const f32x2 uP[2] = {{cur.y - lf, cur.z - cur.x}, {cur.w - cur.y, rt - cur.z}};
    const f32x2 vP[2] = {{dn.x - up.x, dn.y - up.y}, {dn.z - up.z, dn.w - up.w}};

    __syncthreads();   // barrier 1: zero-fill visible before scatter

    // ---- weighted magnitude + octant soft-bin scatter (packed math) ----
    // NOTE: gaussian weight is folded into the pooling tables, not applied here.
    {
        const int base2 = (r * 32 + x0) * 2;
        char* angb = reinterpret_cast<char*>(ang);
        #pragma unroll
        for (int h = 0; h < 2; ++h) {
            const f32x2 u = uP[h], v = vP[h];
            const f32x2 m2 = u * u + v * v;
            const f32x2 marg = m2 * 0.25f + EPS;
            const f32x2 mag = {__builtin_amdgcn_sqrtf(marg.x),
                               __builtin_amdgcn_sqrtf(marg.y)};

            const f32x2 gxe = u + 2e-10f;
            const f32x2 ax = __builtin_elementwise_abs(gxe);
            const f32x2 ay = __builtin_elementwise_abs(v);
            // mx >= 2e-10 always (u is 0 or |u| >= ~6e-8), no guard needed
            const f32x2 mx = __builtin_elementwise_max(ax, ay);
            const f32x2 mn = __builtin_elementwise_min(ax, ay);
            const f32x2 rc = {__builtin_amdgcn_rcpf(mx.x),
                              __builtin_amdgcn_rcpf(mx.y)};
            const f32x2 t = mn * rc;
            const f32x2 s = t * t;
            f32x2 pl = s * (-0.1083947f) + 0.2293632f;          // pre-scaled by 4/pi
            pl = s * pl + (-0.4205503f);
            pl = s * pl + 1.2730689f;
            const f32x2 p  = t * pl;                            // in-octant fraction
            const f32x2 pc = 1.0f - p;

            #pragma unroll
            for (int e = 0; e < 2; ++e) {
                const int ssw = (ay[e] > ax[e]);
                const int sx  = (gxe[e] < 0.0f);
                const int sy  = (v[e] < 0.0f);
                const int bit0 = ssw ^ sx;
                const int oct  = ((sx << 1) | bit0) ^ (sy ? 7 : 0);   // = bin0
                const float w1 = (bit0 ^ sy) ? pc[e] : p[e];
                const float m1 = w1 * mag[e];
                const float m0 = mag[e] - m1;

                const __half2 hh = __float22half2_rn(make_float2(m0, m1));
                unsigned int pk; __builtin_memcpy(&pk, &hh, 4);
                const int t0 = oct << 11;
                const int t1 = (t0 + 2048) & 0x3FFF;
                const int off = base2 + 2 * (2 * h + e);
                *reinterpret_cast<unsigned short*>(angb + t0 + off) = (unsigned short)pk;
                *reinterpret_cast<unsigned short*>(angb + t1 + off) = (unsigned short)(pk >> 16);
            }
        }
    }
    __syncthreads();   // barrier 2: scatter complete

    // ---- GEMM1 (MFMA fp16): x-pooling (w/ G[x]). A = ang (256x32), B^T = WXT ----
    const int l = tid & 63, w = tid >> 6, g = l >> 4, n = l & 15;
    const f16x8 bfrag = *reinterpret_cast<const f16x8*>(WXT.v + n * 32 + g * 8);
    {
        const f32x4 zacc = {0.f, 0.f, 0.f, 0.f};
        #pragma unroll
        for (int tt = 0; tt < 4; ++tt) {
            const int T = w * 4 + tt;                       // row-tile 0..15
            const f16x8 afrag = *reinterpret_cast<const f16x8*>(
                ang + (T * 16 + n) * 32 + g * 8);
            const f32x4 acc = __builtin_amdgcn_mfma_f32_16x16x32_f16(afrag, bfrag, zacc, 0, 0, 0);
            if (n < 4) {
                // C layout: row = T*16 + 4g + reg (= a*32 + y), col = n (= ox)
                const int row = T * 16 + 4 * g;
                const int a = row >> 5, y0 = row & 31;
                const __half2 p01 = __float22half2_rn(make_float2(acc[0], acc[1]));
                const __half2 p23 = __float22half2_rn(make_float2(acc[2], acc[3]));
                unsigned int lo, hi;
                __builtin_memcpy(&lo, &p01, 4);
                __builtin_memcpy(&hi, &p23, 4);
                // r2b[row2 = a*4+ox][y], fp16, row stride 32
                *reinterpret_cast<uint2*>(r2b + (a * 4 + n) * 32 + y0) = make_uint2(lo, hi);
            }
        }
    }
    __syncthreads();   // barrier 3: r2b complete
    if (tid >= 64) return;   // waves 1-3 done

    // ---- GEMM2 (wave 0): y-pooling (w/ G[y]). A = r2b (32x32), B^T = WXT ----
    const f32x4 zacc = {0.f, 0.f, 0.f, 0.f};
    const f16x8 fa0 = *reinterpret_cast<const f16x8*>(r2b + (n)      * 32 + g * 8);
    const f16x8 fa1 = *reinterpret_cast<const f16x8*>(r2b + (16 + n) * 32 + g * 8);
    const f32x4 d0 = __builtin_amdgcn_mfma_f32_16x16x32_f16(fa0, bfrag, zacc, 0, 0, 0);
    const f32x4 d1 = __builtin_amdgcn_mfma_f32_16x16x32_f16(fa1, bfrag, zacc, 0, 0, 0);

    // lane (g,n), reg rr: d0 -> desc[a=g][oy=n][ox=rr], d1 -> desc[a=4+g][oy=n][ox=rr]
    const bool act = (n < 4);
    float q0 = act ? d0[0] : 0.f, q1 = act ? d0[1] : 0.f;
    float q2 = act ? d0[2] : 0.f, q3 = act ? d0[3] : 0.f;
    float q4 = act ? d1[0] : 0.f, q5 = act ? d1[1] : 0.f;
    float q6 = act ? d1[2] : 0.f, q7 = act ? d1[3] : 0.f;

    // ---- norm chain in-wave. Active lanes = {g*16+n, n<4} = coset of span{1,2,16,32},
    //      so xor-offsets 4,8 are redundant (inactive lanes carry exact zeros).
    float ss = q0*q0 + q1*q1 + q2*q2 + q3*q3 + q4*q4 + q5*q5 + q6*q6 + q7*q7;
    ss += __shfl_xor(ss, 1); ss += __shfl_xor(ss, 2);
    ss += __shfl_xor(ss, 16); ss += __shfl_xor(ss, 32);
    const float inv = __builtin_amdgcn_rcpf(fmaxf(__builtin_amdgcn_sqrtf(ss), 1e-12f));
    q0 = fminf(q0 * inv, 0.2f); q1 = fminf(q1 * inv, 0.2f);
    q2 = fminf(q2 * inv, 0.2f); q3 = fminf(q3 * inv, 0.2f);
    q4 = fminf(q4 * inv, 0.2f); q5 = fminf(q5 * inv, 0.2f);
    q6 = fminf(q6 * inv, 0.2f); q7 = fminf(q7 * inv, 0.2f);

    float ss2 = q0*q0 + q1*q1 + q2*q2 + q3*q3 + q4*q4 + q5*q5 + q6*q6 + q7*q7;
    ss2 += __shfl_xor(ss2, 1); ss2 += __shfl_xor(ss2, 2);
    ss2 += __shfl_xor(ss2, 16); ss2 += __shfl_xor(ss2, 32);
    const float inv2 = __builtin_amdgcn_rcpf(fmaxf(__builtin_amdgcn_sqrtf(ss2), 1e-12f));
    q0 *= inv2; q1 *= inv2; q2 *= inv2; q3 *= inv2;
    q4 *= inv2; q5 *= inv2; q6 *= inv2; q7 *= inv2;

    float s1 = q0 + q1 + q2 + q3 + q4 + q5 + q6 + q7;
    s1 += __shfl_xor(s1, 1); s1 += __shfl_xor(s1, 2);
    s1 += __shfl_xor(s1, 16); s1 += __shfl_xor(s1, 32);
    const float inv1 = __builtin_amdgcn_rcpf(fmaxf(s1, 1e-12f));
    q0 = __builtin_amdgcn_sqrtf(fmaf(q0, inv1, EPS));
    q1 = __builtin_amdgcn_sqrtf(fmaf(q1, inv1, EPS));
    q2 = __builtin_amdgcn_sqrtf(fmaf(q2, inv1, EPS));
    q3 = __builtin_amdgcn_sqrtf(fmaf(q3, inv1, EPS));
    q4 = __builtin_amdgcn_sqrtf(fmaf(q4, inv1, EPS));
    q5 = __builtin_amdgcn_sqrtf(fmaf(q5, inv1, EPS));
    q6 = __builtin_amdgcn_sqrtf(fmaf(q6, inv1, EPS));
    q7 = __builtin_amdgcn_sqrtf(fmaf(q7, inv1, EPS));

    if (act) {
        // out idx = a*16 + oy*4 + ox: (d0) 16g + 4n + rr, (d1) 64 + 16g + 4n + rr
        float* op = out + (size_t)b * 128 + 16 * g + 4 * n;
        *reinterpret_cast<float4*>(op)      = make_float4(q0, q1, q2, q3);
        *reinterpret_cast<float4*>(op + 64) = make_float4(q4, q5, q6, q7);
    }
}

extern "C" void kernel_launch(void* const* d_in, const int* in_sizes, int n_in,
                              void* d_out, int out_size, void* d_ws, size_t ws_size,
                              hipStream_t stream) {
    const float* in = (const float*)d_in[0];
    float* out = (float*)d_out;
    const int batch = in_sizes[0] / 1024;   // 32*32 per patch
    sift_desc_kernel<<<batch, 256, 0, stream>>>(in, out);
}

// Round 14
// 31.522 us; speedup vs baseline: 1.2309x; 1.0419x over previous
//
#include <hip/hip_runtime.h>
#include <hip/hip_fp16.h>
#include <math.h>

typedef __attribute__((ext_vector_type(8))) _Float16 f16x8;
typedef __attribute__((ext_vector_type(2))) __fp16 h16x2;
typedef __attribute__((ext_vector_type(4))) float f32x4;
typedef __attribute__((ext_vector_type(2))) float f32x2;

// constexpr exp via Taylor (|x| < 1)
static constexpr double cexp(double x) {
    double s = 1.0, t = 1.0;
    for (int k = 1; k < 24; ++k) { t *= x / k; s += t; }
    return s;
}

// double -> fp16 bits, round-to-nearest (positive normals + zero; our values only)
static constexpr unsigned short f2h_rn(double dv) {
    float f = (float)dv;
    if (f == 0.0f) return 0;
    unsigned u = __builtin_bit_cast(unsigned, f);
    u += 0x1000;                                   // RN at fp16 mantissa boundary
    int e = (int)((u >> 23) & 0xff) - 127 + 15;
    unsigned m = (u >> 13) & 0x3ff;
    return (unsigned short)((e << 10) | m);
}

// Pooling table with gaussian FOLDED IN: W[n][k] = tri12(k-8n+3) * G[k], fp16.
// Serves GEMM1 (k=x, folds G[x]) AND GEMM2 (k=y, folds G[y]) — same geometry.
// tri unnormalized, gaussian unnormalized: global scales cancel in l2norm.
struct alignas(16) WxTbl { unsigned short v[16 * 32]; };
static constexpr WxTbl gen_wx() {
    WxTbl t{};
    for (int n = 0; n < 16; ++n)
        for (int k = 0; k < 32; ++k) {
            double w = 0.0;
            if (n < 4) {
                int kk = k - 8 * n + 3;            // conv ksize=12, stride=8, pad=3
                if (kk >= 0 && kk < 12) {
                    double d = (double)kk - 5.5; if (d < 0) d = -d;
                    w = (6.0 - d) * cexp(-((k - 15.5) * (k - 15.5)) / 1024.0);
                }
            }
            t.v[n * 32 + k] = f2h_rn(w);
        }
    return t;
}
__device__ const WxTbl WXT = gen_wx();

__global__ __launch_bounds__(256, 8) void sift_desc_kernel(
        const float* __restrict__ in, float* __restrict__ out) {
    __shared__ __align__(16) unsigned short ang[8192];  // [bin*32+y][x] fp16, 16 KB
    __shared__ __align__(16) unsigned short r2b[1024];  // [bin*4+ox][y] fp16, 2 KB

    const int b = blockIdx.x, tid = threadIdx.x;
    constexpr float EPS = 1e-10f;

    // zero-fill ang
    {
        const float4 z = make_float4(0.f, 0.f, 0.f, 0.f);
        float4* az = reinterpret_cast<float4*>(ang);
        az[tid] = z; az[tid + 256] = z; az[tid + 512] = z; az[tid + 768] = z;
    }

    // ---- phase 0: row-segment gradients from global (L3-resident) ----
    const int r  = tid >> 3;          // row 0..31
    const int sg = tid & 7;           // segment 0..7
    const int x0 = sg * 4;
    const float* gp = in + (size_t)b * 1024;
    const float4 cur = *reinterpret_cast<const float4*>(gp + r * 32 + x0);
    const int rup = (r > 0) ? r - 1 : 0, rdn = (r < 31) ? r + 1 : 31;
    const float4 up = *reinterpret_cast<const float4*>(gp + rup * 32 + x0);
    const float4 dn = *reinterpret_cast<const float4*>(gp + rdn * 32 + x0);

    const float lfs = __shfl_up(cur.w, 1);
    const float rts = __shfl_down(cur.x, 1);
    const float lf = (sg == 0) ? cur.x : lfs;   // replicate-pad at x=0
    const float rt = (sg == 7) ? cur.w : rts;   // replicate-pad at x=31

    // u = 2*gx, v = 2*gy (scales fold into mag; global scale cancels in l2norm)
    const f32x2 uP[2] = {{cur.y - lf, cur.z - cur.x}, {cur.w - cur.y, rt - cur.z}};
    const f32x2 vP[2] = {{dn.x - up.x, dn.y - up.y}, {dn.z - up.z, dn.w - up.w}};

    __syncthreads();   // barrier 1: zero-fill visible before scatter

    // ---- magnitude + octant soft-bin scatter (single-rsq formulation) ----
    // mag = sqrt(u^2+v^2+4eps) (2x ref scale — cancels); p = asin(mn*rsq)*4/pi.
    {
        const int base2 = (r * 32 + x0) * 2;
        char* angb = reinterpret_cast<char*>(ang);
        #pragma unroll
        for (int h = 0; h < 2; ++h) {
            const f32x2 u = uP[h], v = vP[h];
            const f32x2 m2 = u * u + v * v;
            const f32x2 mq = m2 + 4.0f * EPS;
            const f32x2 rs = {__builtin_amdgcn_rsqf(mq.x),
                              __builtin_amdgcn_rsqf(mq.y)};
            const f32x2 mag = mq * rs;                          // = sqrt(mq)
            const f32x2 au = __builtin_elementwise_abs(u);
            const f32x2 av = __builtin_elementwise_abs(v);
            const f32x2 mn = __builtin_elementwise_min(au, av);
            const f32x2 sb = mn * rs;                           // sin(in-octant angle)
            const f32x2 z  = sb * sb;
            f32x2 pl = z * 0.06264f + 0.05684105f;              // asin*4/pi, odd deg-9
            pl = z * pl + 0.09549297f;
            pl = z * pl + 0.21220659f;
            pl = z * pl + 1.27323954f;
            const f32x2 p  = sb * pl;                           // in-octant fraction [0,1]
            const f32x2 pc = 1.0f - p;

            #pragma unroll
            for (int e = 0; e < 2; ++e) {
                const int ssw = (av[e] > au[e]);
                const int sx  = (u[e] < 0.0f);   // u never -0; |u| is 0 or >= 6e-8
                const int sy  = (v[e] < 0.0f);
                const int bit0 = ssw ^ sx;
                const int oct  = ((sx << 1) | bit0) ^ (sy ? 7 : 0);   // = bin0
                const float w1 = (bit0 ^ sy) ? pc[e] : p[e];
                const float m1 = w1 * mag[e];
                const float m0 = mag[e] - m1;

                const h16x2 hh = __builtin_amdgcn_cvt_pkrtz(m0, m1);  // 1-instr pack
                unsigned int pk; __builtin_memcpy(&pk, &hh, 4);
                const int t0 = oct << 11;
                const int t1 = (t0 + 2048) & 0x3FFF;
                const int off = base2 + 2 * (2 * h + e);
                *reinterpret_cast<unsigned short*>(angb + t0 + off) = (unsigned short)pk;
                *reinterpret_cast<unsigned short*>(angb + t1 + off) = (unsigned short)(pk >> 16);
            }
        }
    }
    __syncthreads();   // barrier 2: scatter complete

    // ---- GEMM1 (MFMA fp16): x-pooling (w/ G[x]). A = ang (256x32), B^T = WXT ----
    const int l = tid & 63, w = tid >> 6, g = l >> 4, n = l & 15;
    const f16x8 bfrag = *reinterpret_cast<const f16x8*>(WXT.v + n * 32 + g * 8);
    {
        const f32x4 zacc = {0.f, 0.f, 0.f, 0.f};
        #pragma unroll
        for (int tt = 0; tt < 4; ++tt) {
            const int T = w * 4 + tt;                       // row-tile 0..15
            const f16x8 afrag = *reinterpret_cast<const f16x8*>(
                ang + (T * 16 + n) * 32 + g * 8);
            const f32x4 acc = __builtin_amdgcn_mfma_f32_16x16x32_f16(afrag, bfrag, zacc, 0, 0, 0);
            if (n < 4) {
                // C layout: row = T*16 + 4g + reg (= a*32 + y), col = n (= ox)
                const int row = T * 16 + 4 * g;
                const int a = row >> 5, y0 = row & 31;
                const __half2 p01 = __float22half2_rn(make_float2(acc[0], acc[1]));
                const __half2 p23 = __float22half2_rn(make_float2(acc[2], acc[3]));
                unsigned int lo, hi;
                __builtin_memcpy(&lo, &p01, 4);
                __builtin_memcpy(&hi, &p23, 4);
                // r2b[row2 = a*4+ox][y], fp16, row stride 32
                *reinterpret_cast<uint2*>(r2b + (a * 4 + n) * 32 + y0) = make_uint2(lo, hi);
            }
        }
    }
    __syncthreads();   // barrier 3: r2b complete
    if (tid >= 64) return;   // waves 1-3 done

    // ---- GEMM2 (wave 0): y-pooling (w/ G[y]). A = r2b (32x32), B^T = WXT ----
    const f32x4 zacc = {0.f, 0.f, 0.f, 0.f};
    const f16x8 fa0 = *reinterpret_cast<const f16x8*>(r2b + (n)      * 32 + g * 8);
    const f16x8 fa1 = *reinterpret_cast<const f16x8*>(r2b + (16 + n) * 32 + g * 8);
    const f32x4 d0 = __builtin_amdgcn_mfma_f32_16x16x32_f16(fa0, bfrag, zacc, 0, 0, 0);
    const f32x4 d1 = __builtin_amdgcn_mfma_f32_16x16x32_f16(fa1, bfrag, zacc, 0, 0, 0);

    // lane (g,n), reg rr: d0 -> desc[a=g][oy=n][ox=rr], d1 -> desc[a=4+g][oy=n][ox=rr]
    const bool act = (n < 4);
    float q0 = act ? d0[0] : 0.f, q1 = act ? d0[1] : 0.f;
    float q2 = act ? d0[2] : 0.f, q3 = act ? d0[3] : 0.f;
    float q4 = act ? d1[0] : 0.f, q5 = act ? d1[1] : 0.f;
    float q6 = act ? d1[2] : 0.f, q7 = act ? d1[3] : 0.f;

    // ---- norm chain in-wave. Active lanes = {g*16+n, n<4} = coset of span{1,2,16,32},
    //      so xor-offsets 4,8 are redundant (inactive lanes carry exact zeros).
    float ss = q0*q0 + q1*q1 + q2*q2 + q3*q3 + q4*q4 + q5*q5 + q6*q6 + q7*q7;
    ss += __shfl_xor(ss, 1); ss += __shfl_xor(ss, 2);
    ss += __shfl_xor(ss, 16); ss += __shfl_xor(ss, 32);
    const float inv = __builtin_amdgcn_rcpf(fmaxf(__builtin_amdgcn_sqrtf(ss), 1e-12f));
    q0 = fminf(q0 * inv, 0.2f); q1 = fminf(q1 * inv, 0.2f);
    q2 = fminf(q2 * inv, 0.2f); q3 = fminf(q3 * inv, 0.2f);
    q4 = fminf(q4 * inv, 0.2f); q5 = fminf(q5 * inv, 0.2f);
    q6 = fminf(q6 * inv, 0.2f); q7 = fminf(q7 * inv, 0.2f);

    float ss2 = q0*q0 + q1*q1 + q2*q2 + q3*q3 + q4*q4 + q5*q5 + q6*q6 + q7*q7;
    ss2 += __shfl_xor(ss2, 1); ss2 += __shfl_xor(ss2, 2);
    ss2 += __shfl_xor(ss2, 16); ss2 += __shfl_xor(ss2, 32);
    const float inv2 = __builtin_amdgcn_rcpf(fmaxf(__builtin_amdgcn_sqrtf(ss2), 1e-12f));
    q0 *= inv2; q1 *= inv2; q2 *= inv2; q3 *= inv2;
    q4 *= inv2; q5 *= inv2; q6 *= inv2; q7 *= inv2;

    float s1 = q0 + q1 + q2 + q3 + q4 + q5 + q6 + q7;
    s1 += __shfl_xor(s1, 1); s1 += __shfl_xor(s1, 2);
    s1 += __shfl_xor(s1, 16); s1 += __shfl_xor(s1, 32);
    const float inv1 = __builtin_amdgcn_rcpf(fmaxf(s1, 1e-12f));
    q0 = __builtin_amdgcn_sqrtf(fmaf(q0, inv1, EPS));
    q1 = __builtin_amdgcn_sqrtf(fmaf(q1, inv1, EPS));
    q2 = __builtin_amdgcn_sqrtf(fmaf(q2, inv1, EPS));
    q3 = __builtin_amdgcn_sqrtf(fmaf(q3, inv1, EPS));
    q4 = __builtin_amdgcn_sqrtf(fmaf(q4, inv1, EPS));
    q5 = __builtin_amdgcn_sqrtf(fmaf(q5, inv1, EPS));
    q6 = __builtin_amdgcn_sqrtf(fmaf(q6, inv1, EPS));
    q7 = __builtin_amdgcn_sqrtf(fmaf(q7, inv1, EPS));

    if (act) {
        // out idx = a*16 + oy*4 + ox: (d0) 16g + 4n + rr, (d1) 64 + 16g + 4n + rr
        float* op = out + (size_t)b * 128 + 16 * g + 4 * n;
        *reinterpret_cast<float4*>(op)      = make_float4(q0, q1, q2, q3);
        *reinterpret_cast<float4*>(op + 64) = make_float4(q4, q5, q6, q7);
    }
}

extern "C" void kernel_launch(void* const* d_in, const int* in_sizes, int n_in,
                              void* d_out, int out_size, void* d_ws, size_t ws_size,
                              hipStream_t stream) {
    const float* in = (const float*)d_in[0];
    float* out = (float*)d_out;
    const int batch = in_sizes[0] / 1024;   // 32*32 per patch
    sift_desc_kernel<<<batch, 256, 0, stream>>>(in, out);
}